// Round 1
// baseline (1248.411 us; speedup 1.0000x reference)
//
#include <hip/hip_runtime.h>
#include <hip/hip_bf16.h>

#define NN 768
#define MD 1024   // hidden1
#define KD 128    // hidden2
#define MC 32     // m-chunk
#define JT 128    // j tile per block
#define SPAD 132  // padded row (floats): 132*4B row stride, 16B aligned

// ---------------- Kernel 1: fill K upper triangle with MLP values ----------
// grid (6, 768): blockIdx.y = row i, blockIdx.x*128 = j0. 256 threads.
// Per-thread 8j x 8k accumulator; k covers all 128 hidden2 units, so the
// ReLU + W3 reduction is fused (h2 never hits memory).
__global__ __launch_bounds__(256) void mlp_fill(
    const float* __restrict__ x,
    const float* __restrict__ W1, const float* __restrict__ b1,
    const float* __restrict__ W2, const float* __restrict__ b2,
    const float* __restrict__ W3, const float* __restrict__ b3,
    float* __restrict__ K)
{
    const int i  = blockIdx.y;
    const int j0 = blockIdx.x * JT;
    if (j0 + JT - 1 < i) return;          // block entirely below diagonal

    __shared__ float sA[MD];              // x_i*W1[m][0] + b1[m]
    __shared__ float sCw[MD];             // W1[m][1]
    __shared__ float sxj[JT];             // x[j0..j0+127]
    __shared__ float S[MC][SPAD];         // sigmoid tile, m-major (j contiguous)
    __shared__ float W2t[MC][SPAD];       // W2 chunk transposed, m-major (k contiguous)

    const int t = threadIdx.x;
    const float xi = x[i];

    for (int m = t; m < MD; m += 256) {
        const float2 w = reinterpret_cast<const float2*>(W1)[m]; // W1[m][0], W1[m][1]
        sA[m]  = fmaf(xi, w.x, b1[m]);
        sCw[m] = w.y;
    }
    if (t < JT) sxj[t] = x[j0 + t];

    const int tk = t & 15;    // 16 k-groups * 8 k
    const int tj = t >> 4;    // 16 j-groups * 8 j  (same-tj = 16 consecutive lanes)
    float w3r[8], b2r[8];
#pragma unroll
    for (int kk = 0; kk < 8; kk++) {
        w3r[kk] = W3[tk * 8 + kk];
        b2r[kk] = b2[tk * 8 + kk];
    }

    float acc[8][8];
#pragma unroll
    for (int jj = 0; jj < 8; jj++)
#pragma unroll
        for (int kk = 0; kk < 8; kk++) acc[jj][kk] = 0.f;

    const int jx   = t & 127;      // j lane for sigmoid compute
    const int mseg = (t >> 7) * 16;

    __syncthreads();
    const float xjv = sxj[jx];

    for (int m0 = 0; m0 < MD; m0 += MC) {
        // ---- stage W2 chunk, transposed: W2t[mm][k] = W2[k][m0+mm] ----
#pragma unroll
        for (int q = 0; q < 4; q++) {
            const int f   = t + q * 256;       // 0..1023 float4 ids
            const int k   = f >> 3;            // 128 rows, 8 float4 each
            const int mm4 = (f & 7) * 4;
            const float4 w = *reinterpret_cast<const float4*>(W2 + k * MD + m0 + mm4);
            W2t[mm4 + 0][k] = w.x;
            W2t[mm4 + 1][k] = w.y;
            W2t[mm4 + 2][k] = w.z;
            W2t[mm4 + 3][k] = w.w;
        }
        // ---- compute sigmoid tile: S[ml][jx] ----
#pragma unroll
        for (int q = 0; q < 16; q++) {
            const int ml = mseg + q;
            const float z = fmaf(xjv, sCw[m0 + ml], sA[m0 + ml]);
            S[ml][jx] = 1.0f / (1.0f + __expf(-z));
        }
        __syncthreads();
        // ---- 64 FMAs per m per thread ----
#pragma unroll 4
        for (int mm = 0; mm < MC; mm++) {
            const float4 s0 = *reinterpret_cast<const float4*>(&S[mm][tj * 8]);
            const float4 s1 = *reinterpret_cast<const float4*>(&S[mm][tj * 8 + 4]);
            const float4 w0 = *reinterpret_cast<const float4*>(&W2t[mm][tk * 8]);
            const float4 w1 = *reinterpret_cast<const float4*>(&W2t[mm][tk * 8 + 4]);
            const float sj[8] = {s0.x, s0.y, s0.z, s0.w, s1.x, s1.y, s1.z, s1.w};
            const float wk[8] = {w0.x, w0.y, w0.z, w0.w, w1.x, w1.y, w1.z, w1.w};
#pragma unroll
            for (int jj = 0; jj < 8; jj++)
#pragma unroll
                for (int kk = 0; kk < 8; kk++)
                    acc[jj][kk] = fmaf(sj[jj], wk[kk], acc[jj][kk]);
        }
        __syncthreads();
    }

    // ---- epilogue: v = sum_k W3[k]*relu(acc + b2[k]) + b3, reduce over tk ----
    const float b3v = b3[0];
#pragma unroll
    for (int jj = 0; jj < 8; jj++) {
        float v = 0.f;
#pragma unroll
        for (int kk = 0; kk < 8; kk++) {
            const float h = acc[jj][kk] + b2r[kk];
            v = fmaf(w3r[kk], fmaxf(h, 0.f), v);
        }
#pragma unroll
        for (int off = 8; off >= 1; off >>= 1)
            v += __shfl_xor(v, off, 16);   // butterfly within the 16-lane tk group
        if (tk == 0) {
            const int j = j0 + tj * 8 + jj;
            if (j >= i) K[i * NN + j] = v + b3v;
        }
    }
}

// ---------------- Kernel 2: C = K^T K (768^3 fp32 GEMM) --------------------
__global__ __launch_bounds__(256) void ktk(const float* __restrict__ K,
                                           float* __restrict__ C)
{
    const int b0 = blockIdx.x * 64;
    const int a0 = blockIdx.y * 64;
    __shared__ float Ka[64][68];
    __shared__ float Kb[64][68];
    const int t  = threadIdx.x;
    const int tb = t & 15;   // 16 groups * 4 b (b contiguous for coalesced store)
    const int ta = t >> 4;   // 16 groups * 4 a

    float acc[4][4];
#pragma unroll
    for (int u = 0; u < 4; u++)
#pragma unroll
        for (int v = 0; v < 4; v++) acc[u][v] = 0.f;

    const int kmax = (a0 < b0 ? a0 : b0) + 64;  // K[k][a]=0 for k>a: skip dead chunks
    for (int k0 = 0; k0 < kmax; k0 += 64) {
#pragma unroll
        for (int q = 0; q < 4; q++) {
            const int f  = t + q * 256;
            const int kk = f >> 4;
            const int c4 = (f & 15) * 4;
            *reinterpret_cast<float4*>(&Ka[kk][c4]) =
                *reinterpret_cast<const float4*>(K + (k0 + kk) * NN + a0 + c4);
            *reinterpret_cast<float4*>(&Kb[kk][c4]) =
                *reinterpret_cast<const float4*>(K + (k0 + kk) * NN + b0 + c4);
        }
        __syncthreads();
#pragma unroll 8
        for (int kk = 0; kk < 64; kk++) {
            const float4 av = *reinterpret_cast<const float4*>(&Ka[kk][ta * 4]);
            const float4 bv = *reinterpret_cast<const float4*>(&Kb[kk][tb * 4]);
            const float a4[4] = {av.x, av.y, av.z, av.w};
            const float b4[4] = {bv.x, bv.y, bv.z, bv.w};
#pragma unroll
            for (int u = 0; u < 4; u++)
#pragma unroll
                for (int v = 0; v < 4; v++)
                    acc[u][v] = fmaf(a4[u], b4[v], acc[u][v]);
        }
        __syncthreads();
    }
#pragma unroll
    for (int u = 0; u < 4; u++) {
        float4 o;
        o.x = acc[u][0]; o.y = acc[u][1]; o.z = acc[u][2]; o.w = acc[u][3];
        *reinterpret_cast<float4*>(C + (a0 + ta * 4 + u) * NN + b0 + tb * 4) = o;
    }
}

extern "C" void kernel_launch(void* const* d_in, const int* in_sizes, int n_in,
                              void* d_out, int out_size, void* d_ws, size_t ws_size,
                              hipStream_t stream)
{
    const float* x  = (const float*)d_in[0];
    const float* W1 = (const float*)d_in[1];
    const float* b1 = (const float*)d_in[2];
    const float* W2 = (const float*)d_in[3];
    const float* b2 = (const float*)d_in[4];
    const float* W3 = (const float*)d_in[5];
    const float* b3 = (const float*)d_in[6];
    float* Kmat = (float*)d_ws;                 // 768*768*4 = 2.36 MB scratch
    float* C    = (float*)d_out;

    hipMemsetAsync(Kmat, 0, NN * NN * sizeof(float), stream);
    mlp_fill<<<dim3(NN / JT, NN), 256, 0, stream>>>(x, W1, b1, W2, b2, W3, b3, Kmat);
    ktk<<<dim3(NN / 64, NN / 64), 256, 0, stream>>>(Kmat, C);
}

// Round 2
// 368.027 us; speedup vs baseline: 3.3922x; 3.3922x over previous
//
#include <hip/hip_runtime.h>
#include <hip/hip_bf16.h>

#define NN 768
#define MD 1024

typedef __attribute__((ext_vector_type(8))) short s16x8;
typedef __attribute__((ext_vector_type(4))) float f32x4;

__device__ __forceinline__ ushort bf16_rn(float f) {
    uint u = __builtin_bit_cast(uint, f);
    u += 0x7FFFu + ((u >> 16) & 1u);
    return (ushort)(u >> 16);
}
__device__ __forceinline__ float bf16_f(ushort h) {
    uint u = ((uint)h) << 16;
    return __builtin_bit_cast(float, u);
}

#define GLOAD16(gsrc, ldst)                                                        \
    __builtin_amdgcn_global_load_lds(                                              \
        (const __attribute__((address_space(1))) void*)(gsrc),                     \
        (__attribute__((address_space(3))) void*)(ldst), 16, 0, 0)

// ---------- one-time: split W2 into bf16 hi/lo, chunk-major + XOR-swizzled -----
// layout: chunk c (m0=c*64): 128 rows(k) x 128B; byte-in-row = (mloc*2) ^ ((k&7)<<4)
__global__ __launch_bounds__(256) void w2split(const float* __restrict__ W2,
                                               ushort* __restrict__ WhiS,
                                               ushort* __restrict__ WloS)
{
    const int id = blockIdx.x * 256 + threadIdx.x;   // 16384 = 128 k * 128 groups
    const int k = id >> 7;
    const int m = (id & 127) * 8;
    const float4 a = *reinterpret_cast<const float4*>(W2 + k * MD + m);
    const float4 b = *reinterpret_cast<const float4*>(W2 + k * MD + m + 4);
    const float w[8] = {a.x, a.y, a.z, a.w, b.x, b.y, b.z, b.w};
    s16x8 h, l;
#pragma unroll
    for (int e = 0; e < 8; ++e) {
        const ushort hb = bf16_rn(w[e]);
        h[e] = (short)hb;
        l[e] = (short)bf16_rn(w[e] - bf16_f(hb));
    }
    const int c = m >> 6;
    const int mloc8 = (m >> 3) & 7;
    const int byte = (mloc8 * 16) ^ ((k & 7) << 4);
    const int off = c * 8192 + ((k * 128 + byte) >> 1);
    *reinterpret_cast<s16x8*>(&WhiS[off]) = h;
    *reinterpret_cast<s16x8*>(&WloS[off]) = l;
}

// ---------- main: K upper triangle via MFMA (hi/lo split, 3-term) --------------
// grid (6, 768), 256 threads = 4 waves in 2x2 (M,N). Per block: 128j x 128k x 1024m.
__global__ __launch_bounds__(256, 2) void mlp_fill_mfma(
    const float* __restrict__ x,
    const float* __restrict__ W1, const float* __restrict__ b1,
    const ushort* __restrict__ WhiS, const ushort* __restrict__ WloS,
    const float* __restrict__ b2, const float* __restrict__ W3,
    const float* __restrict__ b3, float* __restrict__ K)
{
    const int i  = blockIdx.y;
    const int j0 = blockIdx.x * 128;
    if (j0 + 127 < i) return;                 // fully below diagonal

    __shared__ float sA[MD], sCw[MD];
    __shared__ __align__(16) ushort Shi[8192], Slo[8192], Wh[8192], Wl[8192];

    const int t = threadIdx.x;
    const float xi = x[i];
    for (int m = t; m < MD; m += 256) {
        const float2 w = reinterpret_cast<const float2*>(W1)[m];
        sA[m]  = fmaf(xi, w.x, b1[m]);
        sCw[m] = w.y;
    }
    const int jrow = t >> 1, half = t & 1;    // sigmoid: thread owns (jrow, 32 m)
    const float xj = x[j0 + jrow];
    const int wv = t >> 6, lane = t & 63;
    const int wr = wv >> 1, wc = wv & 1;      // wave tile: 64j x 64k
    const int l15 = lane & 15, l4 = lane >> 4;

    f32x4 acc[4][4];
#pragma unroll
    for (int a = 0; a < 4; ++a)
#pragma unroll
        for (int b = 0; b < 4; ++b) acc[a][b] = (f32x4){0.f, 0.f, 0.f, 0.f};

    __syncthreads();                           // sA/sCw ready

    for (int c = 0; c < 16; ++c) {             // K-step: 64 m
        // -- stage W2 chunk: linear gload_lds of pre-swizzled ws data --
        {
            const ushort* sh = WhiS + c * 8192;
            const ushort* sl = WloS + c * 8192;
#pragma unroll
            for (int q = 0; q < 4; ++q) {
                const int off = (wv * 4 + q) * 512;      // ushorts, 1KB/wave-call
                GLOAD16(sh + off + lane * 8, &Wh[off]);
                GLOAD16(sl + off + lane * 8, &Wl[off]);
            }
        }
        // -- sigmoid tile: 128j x 64m, hi/lo bf16, swizzled ds_write_b128 --
#pragma unroll
        for (int g = 0; g < 4; ++g) {
            const int mb = c * 64 + half * 32 + g * 8;
            s16x8 h, l;
#pragma unroll
            for (int e = 0; e < 8; ++e) {
                const float z = fmaf(xj, sCw[mb + e], sA[mb + e]);
                const float s = __builtin_amdgcn_rcpf(1.0f + __expf(-z));
                const ushort hb = bf16_rn(s);
                h[e] = (short)hb;
                l[e] = (short)bf16_rn(s - bf16_f(hb));
            }
            const int byte = (half * 64 + g * 16) ^ ((jrow & 7) << 4);
            const int idx = (jrow * 128 + byte) >> 1;
            *reinterpret_cast<s16x8*>(&Shi[idx]) = h;
            *reinterpret_cast<s16x8*>(&Slo[idx]) = l;
        }
        __syncthreads();
        // -- MFMA: 2 sub-steps of K=32; 16 tiles x 3 terms --
#pragma unroll
        for (int ms = 0; ms < 2; ++ms) {
            s16x8 ah[4], al[4], bh[4], bl[4];
#pragma unroll
            for (int tm = 0; tm < 4; ++tm) {
                const int j = wr * 64 + tm * 16 + l15;
                const int byte = (ms * 64 + l4 * 16) ^ ((j & 7) << 4);
                const int idx = (j * 128 + byte) >> 1;
                ah[tm] = *reinterpret_cast<const s16x8*>(&Shi[idx]);
                al[tm] = *reinterpret_cast<const s16x8*>(&Slo[idx]);
            }
#pragma unroll
            for (int tn = 0; tn < 4; ++tn) {
                const int k = wc * 64 + tn * 16 + l15;
                const int byte = (ms * 64 + l4 * 16) ^ ((k & 7) << 4);
                const int idx = (k * 128 + byte) >> 1;
                bh[tn] = *reinterpret_cast<const s16x8*>(&Wh[idx]);
                bl[tn] = *reinterpret_cast<const s16x8*>(&Wl[idx]);
            }
#pragma unroll
            for (int tm = 0; tm < 4; ++tm)
#pragma unroll
                for (int tn = 0; tn < 4; ++tn) {
                    acc[tm][tn] = __builtin_amdgcn_mfma_f32_16x16x32_bf16(ah[tm], bh[tn], acc[tm][tn], 0, 0, 0);
                    acc[tm][tn] = __builtin_amdgcn_mfma_f32_16x16x32_bf16(ah[tm], bl[tn], acc[tm][tn], 0, 0, 0);
                    acc[tm][tn] = __builtin_amdgcn_mfma_f32_16x16x32_bf16(al[tm], bh[tn], acc[tm][tn], 0, 0, 0);
                }
        }
        __syncthreads();
    }

    // -- epilogue: v = sum_k W3[k]*relu(h2+b2[k]); k split across wc -> atomicAdd
    float w3r[4], b2r[4];
#pragma unroll
    for (int tn = 0; tn < 4; ++tn) {
        const int k = wc * 64 + tn * 16 + l15;
        w3r[tn] = W3[k];
        b2r[tn] = b2[k];
    }
    const float b3v = (wc == 0) ? b3[0] : 0.f;   // add bias only once per (i,j)
#pragma unroll
    for (int tm = 0; tm < 4; ++tm)
#pragma unroll
        for (int r = 0; r < 4; ++r) {
            float v = 0.f;
#pragma unroll
            for (int tn = 0; tn < 4; ++tn)
                v = fmaf(w3r[tn], fmaxf(acc[tm][tn][r] + b2r[tn], 0.f), v);
            v += __shfl_xor(v, 1, 16);
            v += __shfl_xor(v, 2, 16);
            v += __shfl_xor(v, 4, 16);
            v += __shfl_xor(v, 8, 16);
            if (l15 == 0) {
                const int j = j0 + wr * 64 + tm * 16 + l4 * 4 + r;
                if (j >= i) atomicAdd(&K[i * NN + j], v + b3v);
            }
        }
}

// ---------- fallback fp32 MLP kernel (known good, used if ws too small) --------
#define MC 32
#define JT 128
#define SPAD 132
__global__ __launch_bounds__(256) void mlp_fill(
    const float* __restrict__ x,
    const float* __restrict__ W1, const float* __restrict__ b1,
    const float* __restrict__ W2, const float* __restrict__ b2,
    const float* __restrict__ W3, const float* __restrict__ b3,
    float* __restrict__ K)
{
    const int i  = blockIdx.y;
    const int j0 = blockIdx.x * JT;
    if (j0 + JT - 1 < i) return;
    __shared__ float sA[MD];
    __shared__ float sCw[MD];
    __shared__ float sxj[JT];
    __shared__ float S[MC][SPAD];
    __shared__ float W2t[MC][SPAD];
    const int t = threadIdx.x;
    const float xi = x[i];
    for (int m = t; m < MD; m += 256) {
        const float2 w = reinterpret_cast<const float2*>(W1)[m];
        sA[m]  = fmaf(xi, w.x, b1[m]);
        sCw[m] = w.y;
    }
    if (t < JT) sxj[t] = x[j0 + t];
    const int tk = t & 15;
    const int tj = t >> 4;
    float w3r[8], b2r[8];
#pragma unroll
    for (int kk = 0; kk < 8; kk++) {
        w3r[kk] = W3[tk * 8 + kk];
        b2r[kk] = b2[tk * 8 + kk];
    }
    float acc[8][8];
#pragma unroll
    for (int jj = 0; jj < 8; jj++)
#pragma unroll
        for (int kk = 0; kk < 8; kk++) acc[jj][kk] = 0.f;
    const int jx   = t & 127;
    const int mseg = (t >> 7) * 16;
    __syncthreads();
    const float xjv = sxj[jx];
    for (int m0 = 0; m0 < MD; m0 += MC) {
#pragma unroll
        for (int q = 0; q < 4; q++) {
            const int f   = t + q * 256;
            const int k   = f >> 3;
            const int mm4 = (f & 7) * 4;
            const float4 w = *reinterpret_cast<const float4*>(W2 + k * MD + m0 + mm4);
            W2t[mm4 + 0][k] = w.x;
            W2t[mm4 + 1][k] = w.y;
            W2t[mm4 + 2][k] = w.z;
            W2t[mm4 + 3][k] = w.w;
        }
#pragma unroll
        for (int q = 0; q < 16; q++) {
            const int ml = mseg + q;
            const float z = fmaf(xjv, sCw[m0 + ml], sA[m0 + ml]);
            S[ml][jx] = 1.0f / (1.0f + __expf(-z));
        }
        __syncthreads();
#pragma unroll 4
        for (int mm = 0; mm < MC; mm++) {
            const float4 s0 = *reinterpret_cast<const float4*>(&S[mm][tj * 8]);
            const float4 s1 = *reinterpret_cast<const float4*>(&S[mm][tj * 8 + 4]);
            const float4 w0 = *reinterpret_cast<const float4*>(&W2t[mm][tk * 8]);
            const float4 w1 = *reinterpret_cast<const float4*>(&W2t[mm][tk * 8 + 4]);
            const float sj[8] = {s0.x, s0.y, s0.z, s0.w, s1.x, s1.y, s1.z, s1.w};
            const float wk[8] = {w0.x, w0.y, w0.z, w0.w, w1.x, w1.y, w1.z, w1.w};
#pragma unroll
            for (int jj = 0; jj < 8; jj++)
#pragma unroll
                for (int kk = 0; kk < 8; kk++)
                    acc[jj][kk] = fmaf(sj[jj], wk[kk], acc[jj][kk]);
        }
        __syncthreads();
    }
    const float b3v = b3[0];
#pragma unroll
    for (int jj = 0; jj < 8; jj++) {
        float v = 0.f;
#pragma unroll
        for (int kk = 0; kk < 8; kk++) {
            const float h = acc[jj][kk] + b2r[kk];
            v = fmaf(w3r[kk], fmaxf(h, 0.f), v);
        }
#pragma unroll
        for (int off = 8; off >= 1; off >>= 1)
            v += __shfl_xor(v, off, 16);
        if (tk == 0) {
            const int j = j0 + tj * 8 + jj;
            if (j >= i) K[i * NN + j] = v + b3v;
        }
    }
}

// ---------------- Kernel 2: C = K^T K (768^3 fp32 GEMM) --------------------
__global__ __launch_bounds__(256) void ktk(const float* __restrict__ K,
                                           float* __restrict__ C)
{
    const int b0 = blockIdx.x * 64;
    const int a0 = blockIdx.y * 64;
    __shared__ float Ka[64][68];
    __shared__ float Kb[64][68];
    const int t  = threadIdx.x;
    const int tb = t & 15;
    const int ta = t >> 4;
    float acc[4][4];
#pragma unroll
    for (int u = 0; u < 4; u++)
#pragma unroll
        for (int v = 0; v < 4; v++) acc[u][v] = 0.f;
    const int kmax = (a0 < b0 ? a0 : b0) + 64;
    for (int k0 = 0; k0 < kmax; k0 += 64) {
#pragma unroll
        for (int q = 0; q < 4; q++) {
            const int f  = t + q * 256;
            const int kk = f >> 4;
            const int c4 = (f & 15) * 4;
            *reinterpret_cast<float4*>(&Ka[kk][c4]) =
                *reinterpret_cast<const float4*>(K + (k0 + kk) * NN + a0 + c4);
            *reinterpret_cast<float4*>(&Kb[kk][c4]) =
                *reinterpret_cast<const float4*>(K + (k0 + kk) * NN + b0 + c4);
        }
        __syncthreads();
#pragma unroll 8
        for (int kk = 0; kk < 64; kk++) {
            const float4 av = *reinterpret_cast<const float4*>(&Ka[kk][ta * 4]);
            const float4 bv = *reinterpret_cast<const float4*>(&Kb[kk][tb * 4]);
            const float a4[4] = {av.x, av.y, av.z, av.w};
            const float b4[4] = {bv.x, bv.y, bv.z, bv.w};
#pragma unroll
            for (int u = 0; u < 4; u++)
#pragma unroll
                for (int v = 0; v < 4; v++)
                    acc[u][v] = fmaf(a4[u], b4[v], acc[u][v]);
        }
        __syncthreads();
    }
#pragma unroll
    for (int u = 0; u < 4; u++) {
        float4 o;
        o.x = acc[u][0]; o.y = acc[u][1]; o.z = acc[u][2]; o.w = acc[u][3];
        *reinterpret_cast<float4*>(C + (a0 + ta * 4 + u) * NN + b0 + tb * 4) = o;
    }
}

extern "C" void kernel_launch(void* const* d_in, const int* in_sizes, int n_in,
                              void* d_out, int out_size, void* d_ws, size_t ws_size,
                              hipStream_t stream)
{
    const float* x  = (const float*)d_in[0];
    const float* W1 = (const float*)d_in[1];
    const float* b1 = (const float*)d_in[2];
    const float* W2 = (const float*)d_in[3];
    const float* b2 = (const float*)d_in[4];
    const float* W3 = (const float*)d_in[5];
    const float* b3 = (const float*)d_in[6];
    float* Kmat = (float*)d_ws;                       // 2,359,296 B
    float* C    = (float*)d_out;

    const size_t kBytes = (size_t)NN * NN * sizeof(float);
    const size_t need   = kBytes + 2 * 262144;

    hipMemsetAsync(Kmat, 0, kBytes, stream);
    if (ws_size >= need) {
        ushort* WhiS = (ushort*)((char*)d_ws + kBytes);
        ushort* WloS = WhiS + 131072;
        w2split<<<64, 256, 0, stream>>>(W2, WhiS, WloS);
        mlp_fill_mfma<<<dim3(6, NN), 256, 0, stream>>>(x, W1, b1, WhiS, WloS,
                                                       b2, W3, b3, Kmat);
    } else {
        mlp_fill<<<dim3(6, NN), 256, 0, stream>>>(x, W1, b1, W2, b2, W3, b3, Kmat);
    }
    ktk<<<dim3(NN / 64, NN / 64), 256, 0, stream>>>(Kmat, C);
}

// Round 3
// 267.111 us; speedup vs baseline: 4.6738x; 1.3778x over previous
//
#include <hip/hip_runtime.h>
#include <hip/hip_bf16.h>

#define NN 768
#define MD 1024
#define NPAIR 295296            // 768*769/2
#define NPBLK 1154              // ceil(NPAIR/256)

typedef __attribute__((ext_vector_type(8))) short s16x8;
typedef __attribute__((ext_vector_type(4))) float f32x4;

__device__ __forceinline__ ushort bf16_rn(float f) {
    uint u = __builtin_bit_cast(uint, f);
    u += 0x7FFFu + ((u >> 16) & 1u);
    return (ushort)(u >> 16);
}
__device__ __forceinline__ float bf16_f(ushort h) {
    uint u = ((uint)h) << 16;
    return __builtin_bit_cast(float, u);
}

// inverse triangular index: p -> (i,j), off(i) = i*(1537-i)/2, j = i + p - off(i)
__device__ __forceinline__ void ptoij(int p, int& io, int& jo) {
    const float disc = (float)(1537 * 1537 - 8 * p);
    int i = (int)((1537.0f - sqrtf(disc)) * 0.5f);
    i = i < 0 ? 0 : (i > 767 ? 767 : i);
    while (i > 0 && p < i * (1537 - i) / 2) --i;
    while (i < 767 && p >= (i + 1) * (1536 - i) / 2) ++i;
    io = i;
    jo = i + (p - i * (1537 - i) / 2);
}

#define GLOAD16(gsrc, ldst)                                                        \
    __builtin_amdgcn_global_load_lds(                                              \
        (const __attribute__((address_space(1))) void*)(gsrc),                     \
        (__attribute__((address_space(3))) void*)(ldst), 16, 0, 0)

// ---------- one-time: split W2 into bf16 hi/lo (Dekker), chunk-major + swizzled
// chunk c (m0=c*64): 128 rows(k) x 128B; byte-in-row = (mloc8*16) ^ ((k&7)<<4)
__global__ __launch_bounds__(256) void w2split(const float* __restrict__ W2,
                                               ushort* __restrict__ WhiS,
                                               ushort* __restrict__ WloS)
{
    const int id = blockIdx.x * 256 + threadIdx.x;   // 16384 = 128 k * 128 groups
    const int k = id >> 7;
    const int m = (id & 127) * 8;
    const float4 a = *reinterpret_cast<const float4*>(W2 + k * MD + m);
    const float4 b = *reinterpret_cast<const float4*>(W2 + k * MD + m + 4);
    const float w[8] = {a.x, a.y, a.z, a.w, b.x, b.y, b.z, b.w};
    s16x8 h, l;
#pragma unroll
    for (int e = 0; e < 8; ++e) {
        const ushort hb = bf16_rn(w[e]);
        h[e] = (short)hb;
        l[e] = (short)bf16_rn(w[e] - bf16_f(hb));   // exact residual, then RNE
    }
    const int c = m >> 6;
    const int mloc8 = (m >> 3) & 7;
    const int byte = (mloc8 * 16) ^ ((k & 7) << 4);
    const int off = c * 8192 + ((k * 128 + byte) >> 1);
    *reinterpret_cast<s16x8*>(&WhiS[off]) = h;
    *reinterpret_cast<s16x8*>(&WloS[off]) = l;
}

// ---------- main: pair-flattened MLP. 4 waves, each 64 pairs x 128 k ----------
__global__ __launch_bounds__(256, 2) void mlp_pairs(
    const float* __restrict__ x,
    const float* __restrict__ W1, const float* __restrict__ b1,
    const ushort* __restrict__ WhiS, const ushort* __restrict__ WloS,
    const float* __restrict__ b2, const float* __restrict__ W3,
    const float* __restrict__ b3, float* __restrict__ K)
{
    __shared__ __align__(16) float sa[MD], sc[MD], sb[MD];
    __shared__ __align__(16) ushort Wh[8192], Wl[8192];

    const int t = threadIdx.x;
    const int lane = t & 63, wv = t >> 6;
    const int l15 = lane & 15, l4 = lane >> 4;

    for (int m = t; m < MD; m += 256) {
        const float2 w = reinterpret_cast<const float2*>(W1)[m];
        sa[m] = w.x;
        sc[m] = w.y;
        sb[m] = b1[m];
    }

    const int pairbase = blockIdx.x * 256 + wv * 64;

    // (xi, xj) for the 4 A-frag rows this lane computes sigmoids for
    float xia[4], xja[4];
#pragma unroll
    for (int tm = 0; tm < 4; ++tm) {
        const int p = pairbase + tm * 16 + l15;
        if (p < NPAIR) {
            int i, j;
            ptoij(p, i, j);
            xia[tm] = x[i];
            xja[tm] = x[j];
        } else {
            xia[tm] = 0.f;
            xja[tm] = 0.f;
        }
    }

    f32x4 acc[4][2][4];
#pragma unroll
    for (int tm = 0; tm < 4; ++tm)
#pragma unroll
        for (int th = 0; th < 2; ++th)
#pragma unroll
            for (int tn = 0; tn < 4; ++tn) acc[tm][th][tn] = (f32x4){0.f, 0.f, 0.f, 0.f};

    __syncthreads();   // sa/sc/sb ready

    for (int c = 0; c < 16; ++c) {       // K-step: 64 m
        // stage W2 hi/lo chunk (pre-swizzled in ws, linear LDS dest)
        {
            const ushort* sh = WhiS + c * 8192;
            const ushort* sl = WloS + c * 8192;
#pragma unroll
            for (int q = 0; q < 4; ++q) {
                const int off = (wv * 4 + q) * 512;
                GLOAD16(sh + off + lane * 8, &Wh[off]);
                GLOAD16(sl + off + lane * 8, &Wl[off]);
            }
        }
        // in-lane sigmoids -> A-frags (hides staging latency under VALU)
        s16x8 ah[2][4];
#pragma unroll
        for (int ks = 0; ks < 2; ++ks) {
            const int m0 = c * 64 + ks * 32 + l4 * 8;
            float av[8], cv[8], bv[8];
            *reinterpret_cast<f32x4*>(av)     = *reinterpret_cast<const f32x4*>(&sa[m0]);
            *reinterpret_cast<f32x4*>(av + 4) = *reinterpret_cast<const f32x4*>(&sa[m0 + 4]);
            *reinterpret_cast<f32x4*>(cv)     = *reinterpret_cast<const f32x4*>(&sc[m0]);
            *reinterpret_cast<f32x4*>(cv + 4) = *reinterpret_cast<const f32x4*>(&sc[m0 + 4]);
            *reinterpret_cast<f32x4*>(bv)     = *reinterpret_cast<const f32x4*>(&sb[m0]);
            *reinterpret_cast<f32x4*>(bv + 4) = *reinterpret_cast<const f32x4*>(&sb[m0 + 4]);
#pragma unroll
            for (int tm = 0; tm < 4; ++tm) {
                s16x8 fr;
#pragma unroll
                for (int e = 0; e < 8; ++e) {
                    const float z = fmaf(xia[tm], av[e], fmaf(xja[tm], cv[e], bv[e]));
                    const float s = __builtin_amdgcn_rcpf(1.0f + __expf(-z));
                    fr[e] = (short)bf16_rn(s);
                }
                ah[ks][tm] = fr;
            }
        }
        __syncthreads();   // W chunk resident (vmcnt drained by barrier)
#pragma unroll
        for (int ks = 0; ks < 2; ++ks) {
#pragma unroll
            for (int th = 0; th < 2; ++th) {
                s16x8 bh[4], bl[4];
#pragma unroll
                for (int tn = 0; tn < 4; ++tn) {
                    const int k = th * 64 + tn * 16 + l15;
                    const int byte = (ks * 64 + l4 * 16) ^ ((k & 7) << 4);
                    const int idx = (k * 128 + byte) >> 1;
                    bh[tn] = *reinterpret_cast<const s16x8*>(&Wh[idx]);
                    bl[tn] = *reinterpret_cast<const s16x8*>(&Wl[idx]);
                }
#pragma unroll
                for (int tm = 0; tm < 4; ++tm)
#pragma unroll
                    for (int tn = 0; tn < 4; ++tn) {
                        acc[tm][th][tn] = __builtin_amdgcn_mfma_f32_16x16x32_bf16(
                            ah[ks][tm], bh[tn], acc[tm][th][tn], 0, 0, 0);
                        acc[tm][th][tn] = __builtin_amdgcn_mfma_f32_16x16x32_bf16(
                            ah[ks][tm], bl[tn], acc[tm][th][tn], 0, 0, 0);
                    }
            }
        }
        __syncthreads();   // all waves done reading before next stage overwrites
    }

    // epilogue: v = sum_k W3[k]*relu(h2 + b2[k]) + b3; reduce over 16 lanes (k)
    float w3v[2][4], b2v[2][4];
#pragma unroll
    for (int th = 0; th < 2; ++th)
#pragma unroll
        for (int tn = 0; tn < 4; ++tn) {
            const int k = th * 64 + tn * 16 + l15;
            w3v[th][tn] = W3[k];
            b2v[th][tn] = b2[k];
        }
    const float b3v = b3[0];
#pragma unroll
    for (int tm = 0; tm < 4; ++tm)
#pragma unroll
        for (int r = 0; r < 4; ++r) {
            float v = 0.f;
#pragma unroll
            for (int th = 0; th < 2; ++th)
#pragma unroll
                for (int tn = 0; tn < 4; ++tn)
                    v = fmaf(w3v[th][tn], fmaxf(acc[tm][th][tn][r] + b2v[th][tn], 0.f), v);
            v += __shfl_xor(v, 1, 16);
            v += __shfl_xor(v, 2, 16);
            v += __shfl_xor(v, 4, 16);
            v += __shfl_xor(v, 8, 16);
            if (l15 == 0) {
                const int p = pairbase + tm * 16 + l4 * 4 + r;
                if (p < NPAIR) {
                    int i, j;
                    ptoij(p, i, j);
                    K[i * NN + j] = v + b3v;
                }
            }
        }
}

// ---------- fallback fp32 MLP kernel (only if ws too small; never expected) ----
#define MC 32
#define JT 128
#define SPAD 132
__global__ __launch_bounds__(256) void mlp_fill(
    const float* __restrict__ x,
    const float* __restrict__ W1, const float* __restrict__ b1,
    const float* __restrict__ W2, const float* __restrict__ b2,
    const float* __restrict__ W3, const float* __restrict__ b3,
    float* __restrict__ K)
{
    const int i  = blockIdx.y;
    const int j0 = blockIdx.x * JT;
    if (j0 + JT - 1 < i) return;
    __shared__ float sA[MD];
    __shared__ float sCw[MD];
    __shared__ float sxj[JT];
    __shared__ float S[MC][SPAD];
    __shared__ float W2t[MC][SPAD];
    const int t = threadIdx.x;
    const float xi = x[i];
    for (int m = t; m < MD; m += 256) {
        const float2 w = reinterpret_cast<const float2*>(W1)[m];
        sA[m]  = fmaf(xi, w.x, b1[m]);
        sCw[m] = w.y;
    }
    if (t < JT) sxj[t] = x[j0 + t];
    const int tk = t & 15;
    const int tj = t >> 4;
    float w3r[8], b2r[8];
#pragma unroll
    for (int kk = 0; kk < 8; kk++) {
        w3r[kk] = W3[tk * 8 + kk];
        b2r[kk] = b2[tk * 8 + kk];
    }
    float acc[8][8];
#pragma unroll
    for (int jj = 0; jj < 8; jj++)
#pragma unroll
        for (int kk = 0; kk < 8; kk++) acc[jj][kk] = 0.f;
    const int jx   = t & 127;
    const int mseg = (t >> 7) * 16;
    __syncthreads();
    const float xjv = sxj[jx];
    for (int m0 = 0; m0 < MD; m0 += MC) {
#pragma unroll
        for (int q = 0; q < 4; q++) {
            const int f   = t + q * 256;
            const int k   = f >> 3;
            const int mm4 = (f & 7) * 4;
            const float4 w = *reinterpret_cast<const float4*>(W2 + k * MD + m0 + mm4);
            W2t[mm4 + 0][k] = w.x;
            W2t[mm4 + 1][k] = w.y;
            W2t[mm4 + 2][k] = w.z;
            W2t[mm4 + 3][k] = w.w;
        }
#pragma unroll
        for (int q = 0; q < 16; q++) {
            const int ml = mseg + q;
            const float z = fmaf(xjv, sCw[m0 + ml], sA[m0 + ml]);
            S[ml][jx] = 1.0f / (1.0f + __expf(-z));
        }
        __syncthreads();
#pragma unroll 4
        for (int mm = 0; mm < MC; mm++) {
            const float4 s0 = *reinterpret_cast<const float4*>(&S[mm][tj * 8]);
            const float4 s1 = *reinterpret_cast<const float4*>(&S[mm][tj * 8 + 4]);
            const float4 w0 = *reinterpret_cast<const float4*>(&W2t[mm][tk * 8]);
            const float4 w1 = *reinterpret_cast<const float4*>(&W2t[mm][tk * 8 + 4]);
            const float sj[8] = {s0.x, s0.y, s0.z, s0.w, s1.x, s1.y, s1.z, s1.w};
            const float wk[8] = {w0.x, w0.y, w0.z, w0.w, w1.x, w1.y, w1.z, w1.w};
#pragma unroll
            for (int jj = 0; jj < 8; jj++)
#pragma unroll
                for (int kk = 0; kk < 8; kk++)
                    acc[jj][kk] = fmaf(sj[jj], wk[kk], acc[jj][kk]);
        }
        __syncthreads();
    }
    const float b3v = b3[0];
#pragma unroll
    for (int jj = 0; jj < 8; jj++) {
        float v = 0.f;
#pragma unroll
        for (int kk = 0; kk < 8; kk++) {
            const float h = acc[jj][kk] + b2r[kk];
            v = fmaf(w3r[kk], fmaxf(h, 0.f), v);
        }
#pragma unroll
        for (int off = 8; off >= 1; off >>= 1)
            v += __shfl_xor(v, off, 16);
        if (tk == 0) {
            const int j = j0 + tj * 8 + jj;
            if (j >= i) K[i * NN + j] = v + b3v;
        }
    }
}

// ---------------- Kernel 2: C = K^T K (768^3 fp32 GEMM) --------------------
__global__ __launch_bounds__(256) void ktk(const float* __restrict__ K,
                                           float* __restrict__ C)
{
    const int b0 = blockIdx.x * 64;
    const int a0 = blockIdx.y * 64;
    __shared__ float Ka[64][68];
    __shared__ float Kb[64][68];
    const int t  = threadIdx.x;
    const int tb = t & 15;
    const int ta = t >> 4;
    float acc[4][4];
#pragma unroll
    for (int u = 0; u < 4; u++)
#pragma unroll
        for (int v = 0; v < 4; v++) acc[u][v] = 0.f;
    const int kmax = (a0 < b0 ? a0 : b0) + 64;
    for (int k0 = 0; k0 < kmax; k0 += 64) {
#pragma unroll
        for (int q = 0; q < 4; q++) {
            const int f  = t + q * 256;
            const int kk = f >> 4;
            const int c4 = (f & 15) * 4;
            *reinterpret_cast<float4*>(&Ka[kk][c4]) =
                *reinterpret_cast<const float4*>(K + (k0 + kk) * NN + a0 + c4);
            *reinterpret_cast<float4*>(&Kb[kk][c4]) =
                *reinterpret_cast<const float4*>(K + (k0 + kk) * NN + b0 + c4);
        }
        __syncthreads();
#pragma unroll 8
        for (int kk = 0; kk < 64; kk++) {
            const float4 av = *reinterpret_cast<const float4*>(&Ka[kk][ta * 4]);
            const float4 bv = *reinterpret_cast<const float4*>(&Kb[kk][tb * 4]);
            const float a4[4] = {av.x, av.y, av.z, av.w};
            const float b4[4] = {bv.x, bv.y, bv.z, bv.w};
#pragma unroll
            for (int u = 0; u < 4; u++)
#pragma unroll
                for (int v = 0; v < 4; v++)
                    acc[u][v] = fmaf(a4[u], b4[v], acc[u][v]);
        }
        __syncthreads();
    }
#pragma unroll
    for (int u = 0; u < 4; u++) {
        float4 o;
        o.x = acc[u][0]; o.y = acc[u][1]; o.z = acc[u][2]; o.w = acc[u][3];
        *reinterpret_cast<float4*>(C + (a0 + ta * 4 + u) * NN + b0 + tb * 4) = o;
    }
}

extern "C" void kernel_launch(void* const* d_in, const int* in_sizes, int n_in,
                              void* d_out, int out_size, void* d_ws, size_t ws_size,
                              hipStream_t stream)
{
    const float* x  = (const float*)d_in[0];
    const float* W1 = (const float*)d_in[1];
    const float* b1 = (const float*)d_in[2];
    const float* W2 = (const float*)d_in[3];
    const float* b2 = (const float*)d_in[4];
    const float* W3 = (const float*)d_in[5];
    const float* b3 = (const float*)d_in[6];
    float* Kmat = (float*)d_ws;                       // 2,359,296 B
    float* C    = (float*)d_out;

    const size_t kBytes = (size_t)NN * NN * sizeof(float);
    const size_t need   = kBytes + 2 * 262144;        // + W2 hi/lo bf16

    hipMemsetAsync(Kmat, 0, kBytes, stream);
    if (ws_size >= need) {
        ushort* WhiS = (ushort*)((char*)d_ws + kBytes);
        ushort* WloS = WhiS + 131072;
        w2split<<<64, 256, 0, stream>>>(W2, WhiS, WloS);
        mlp_pairs<<<NPBLK, 256, 0, stream>>>(x, W1, b1, WhiS, WloS, b2, W3, b3, Kmat);
    } else {
        mlp_fill<<<dim3(6, NN), 256, 0, stream>>>(x, W1, b1, W2, b2, W3, b3, Kmat);
    }
    ktk<<<dim3(NN / 64, NN / 64), 256, 0, stream>>>(Kmat, C);
}

// Round 4
// 256.040 us; speedup vs baseline: 4.8758x; 1.0432x over previous
//
#include <hip/hip_runtime.h>
#include <hip/hip_bf16.h>

#define NN 768
#define MD 1024
#define NPAIR 295296            // 768*769/2
#define NPBLK 1154              // ceil(NPAIR/256)

typedef __attribute__((ext_vector_type(8))) short s16x8;
typedef __attribute__((ext_vector_type(4))) float f32x4;
typedef __attribute__((ext_vector_type(2))) __bf16 b16x2;

__device__ __forceinline__ ushort bf16_rn(float f) {
    uint u = __builtin_bit_cast(uint, f);
    u += 0x7FFFu + ((u >> 16) & 1u);
    return (ushort)(u >> 16);
}

// inverse triangular index: p -> (i,j), off(i) = i*(1537-i)/2, j = i + p - off(i)
__device__ __forceinline__ void ptoij(int p, int& io, int& jo) {
    const float disc = (float)(1537 * 1537 - 8 * p);
    int i = (int)((1537.0f - sqrtf(disc)) * 0.5f);
    i = i < 0 ? 0 : (i > 767 ? 767 : i);
    while (i > 0 && p < i * (1537 - i) / 2) --i;
    while (i < 767 && p >= (i + 1) * (1536 - i) / 2) ++i;
    io = i;
    jo = i + (p - i * (1537 - i) / 2);
}

#define GLOAD16(gsrc, ldst)                                                        \
    __builtin_amdgcn_global_load_lds(                                              \
        (const __attribute__((address_space(1))) void*)(gsrc),                     \
        (__attribute__((address_space(3))) void*)(ldst), 16, 0, 0)

// ---------- one-time: W2 -> bf16 (RNE), chunk-major + XOR-swizzled -------------
// chunk c (m0=c*64): 128 rows(k) x 128B; byte-in-row = (mloc8*16) ^ ((k&7)<<4)
__global__ __launch_bounds__(256) void w2bf16(const float* __restrict__ W2,
                                              ushort* __restrict__ WhiS)
{
    const int id = blockIdx.x * 256 + threadIdx.x;   // 16384 = 128 k * 128 groups
    const int k = id >> 7;
    const int m = (id & 127) * 8;
    const float4 a = *reinterpret_cast<const float4*>(W2 + k * MD + m);
    const float4 b = *reinterpret_cast<const float4*>(W2 + k * MD + m + 4);
    const float w[8] = {a.x, a.y, a.z, a.w, b.x, b.y, b.z, b.w};
    s16x8 h;
#pragma unroll
    for (int e = 0; e < 8; ++e) h[e] = (short)bf16_rn(w[e]);
    const int c = m >> 6;
    const int mloc8 = (m >> 3) & 7;
    const int byte = (mloc8 * 16) ^ ((k & 7) << 4);
    const int off = c * 8192 + ((k * 128 + byte) >> 1);
    *reinterpret_cast<s16x8*>(&WhiS[off]) = h;
}

// ---- macros for the pipelined main loop (use ambient locals) ------------------
#define STAGE(cc, buf)                                                       \
    {                                                                        \
        const ushort* sh_ = WhiS + (cc) * 8192;                              \
        _Pragma("unroll")                                                    \
        for (int q_ = 0; q_ < 4; ++q_) {                                     \
            const int off_ = (wv * 4 + q_) * 512;                            \
            GLOAD16(sh_ + off_ + lane * 8, &Wh[buf][off_]);                  \
        }                                                                    \
    }

#define SIG_CHUNK(cc, dst)                                                   \
    {                                                                        \
        _Pragma("unroll")                                                    \
        for (int ks_ = 0; ks_ < 2; ++ks_) {                                  \
            const int m0_ = (cc) * 64 + ks_ * 32 + l4 * 8;                   \
            const f32x4 a0_ = *reinterpret_cast<const f32x4*>(&sa[m0_]);     \
            const f32x4 a1_ = *reinterpret_cast<const f32x4*>(&sa[m0_ + 4]); \
            const f32x4 c0_ = *reinterpret_cast<const f32x4*>(&sc[m0_]);     \
            const f32x4 c1_ = *reinterpret_cast<const f32x4*>(&sc[m0_ + 4]); \
            const f32x4 b0_ = *reinterpret_cast<const f32x4*>(&sb[m0_]);     \
            const f32x4 b1_ = *reinterpret_cast<const f32x4*>(&sb[m0_ + 4]); \
            _Pragma("unroll")                                                \
            for (int tm_ = 0; tm_ < 4; ++tm_) {                              \
                float s_[8];                                                 \
                _Pragma("unroll")                                            \
                for (int e_ = 0; e_ < 4; ++e_) {                             \
                    const float z0_ = fmaf(xia[tm_], a0_[e_], fmaf(xja[tm_], c0_[e_], b0_[e_])); \
                    const float z1_ = fmaf(xia[tm_], a1_[e_], fmaf(xja[tm_], c1_[e_], b1_[e_])); \
                    s_[e_]     = __builtin_amdgcn_rcpf(1.0f + __expf(-z0_)); \
                    s_[e_ + 4] = __builtin_amdgcn_rcpf(1.0f + __expf(-z1_)); \
                }                                                            \
                union { s16x8 v; uint u[4]; } fr_;                           \
                _Pragma("unroll")                                            \
                for (int h_ = 0; h_ < 4; ++h_) {                             \
                    b16x2 p_;                                                \
                    p_.x = (__bf16)s_[2 * h_];                               \
                    p_.y = (__bf16)s_[2 * h_ + 1];                           \
                    fr_.u[h_] = __builtin_bit_cast(uint, p_);                \
                }                                                            \
                dst[ks_][tm_] = fr_.v;                                       \
            }                                                                \
        }                                                                    \
    }

#define MFMA_STEP(buf, src)                                                  \
    {                                                                        \
        _Pragma("unroll")                                                    \
        for (int ks_ = 0; ks_ < 2; ++ks_) {                                  \
            _Pragma("unroll")                                                \
            for (int th_ = 0; th_ < 2; ++th_) {                              \
                s16x8 bh_[4];                                                \
                _Pragma("unroll")                                            \
                for (int tn_ = 0; tn_ < 4; ++tn_) {                          \
                    const int k_ = th_ * 64 + tn_ * 16 + l15;                \
                    const int byte_ = (ks_ * 64 + l4 * 16) ^ ((k_ & 7) << 4);\
                    const int idx_ = (k_ * 128 + byte_) >> 1;                \
                    bh_[tn_] = *reinterpret_cast<const s16x8*>(&Wh[buf][idx_]); \
                }                                                            \
                __builtin_amdgcn_s_setprio(1);                               \
                _Pragma("unroll")                                            \
                for (int tm_ = 0; tm_ < 4; ++tm_)                            \
                    _Pragma("unroll")                                        \
                    for (int tn_ = 0; tn_ < 4; ++tn_)                        \
                        acc[tm_][th_][tn_] = __builtin_amdgcn_mfma_f32_16x16x32_bf16( \
                            src[ks_][tm_], bh_[tn_], acc[tm_][th_][tn_], 0, 0, 0);    \
                __builtin_amdgcn_s_setprio(0);                               \
            }                                                                \
        }                                                                    \
    }

// ---------- main: pair-flattened MLP, 1-term bf16, dbuf + pipelined sigmoid ----
__global__ __launch_bounds__(256, 2) void mlp_pairs(
    const float* __restrict__ x,
    const float* __restrict__ W1, const float* __restrict__ b1,
    const ushort* __restrict__ WhiS,
    const float* __restrict__ b2, const float* __restrict__ W3,
    const float* __restrict__ b3, float* __restrict__ K)
{
    __shared__ __align__(16) float sa[MD], sc[MD], sb[MD];
    __shared__ __align__(16) ushort Wh[2][8192];

    const int t = threadIdx.x;
    const int lane = t & 63, wv = t >> 6;
    const int l15 = lane & 15, l4 = lane >> 4;

    for (int m = t; m < MD; m += 256) {
        const float2 w = reinterpret_cast<const float2*>(W1)[m];
        sa[m] = w.x;
        sc[m] = w.y;
        sb[m] = b1[m];
    }

    const int pairbase = blockIdx.x * 256 + wv * 64;

    float xia[4], xja[4];
#pragma unroll
    for (int tm = 0; tm < 4; ++tm) {
        const int p = pairbase + tm * 16 + l15;
        if (p < NPAIR) {
            int i, j;
            ptoij(p, i, j);
            xia[tm] = x[i];
            xja[tm] = x[j];
        } else {
            xia[tm] = 0.f;
            xja[tm] = 0.f;
        }
    }

    f32x4 acc[4][2][4];
#pragma unroll
    for (int a = 0; a < 4; ++a)
#pragma unroll
        for (int th = 0; th < 2; ++th)
#pragma unroll
            for (int b = 0; b < 4; ++b) acc[a][th][b] = (f32x4){0.f, 0.f, 0.f, 0.f};

    STAGE(0, 0);
    __syncthreads();                 // sa/sc/sb written AND Wh[0] staged (vmcnt drained)

    s16x8 ahE[2][4], ahO[2][4];
    SIG_CHUNK(0, ahE);

    for (int cc = 0; cc < 8; ++cc) {
        const int c1 = cc * 2 + 1;
        STAGE(c1, 1);                // issue early; drains at mid barrier
        SIG_CHUNK(c1, ahO);          // VALU, interleaves with MFMA below
        MFMA_STEP(0, ahE);
        __syncthreads();             // Wh[1] ready; all reads of Wh[0] done
        if (cc < 7) {
            STAGE(c1 + 1, 0);
            SIG_CHUNK(c1 + 1, ahE);
        }
        MFMA_STEP(1, ahO);
        __syncthreads();             // Wh[0] ready; all reads of Wh[1] done
    }

    // epilogue: v = sum_k W3[k]*relu(h2 + b2[k]) + b3; reduce over 16 lanes (k)
    float w3v[2][4], b2v[2][4];
#pragma unroll
    for (int th = 0; th < 2; ++th)
#pragma unroll
        for (int tn = 0; tn < 4; ++tn) {
            const int k = th * 64 + tn * 16 + l15;
            w3v[th][tn] = W3[k];
            b2v[th][tn] = b2[k];
        }
    const float b3v = b3[0];
#pragma unroll
    for (int tm = 0; tm < 4; ++tm)
#pragma unroll
        for (int r = 0; r < 4; ++r) {
            float v = 0.f;
#pragma unroll
            for (int th = 0; th < 2; ++th)
#pragma unroll
                for (int tn = 0; tn < 4; ++tn)
                    v = fmaf(w3v[th][tn], fmaxf(acc[tm][th][tn][r] + b2v[th][tn], 0.f), v);
            v += __shfl_xor(v, 1, 16);
            v += __shfl_xor(v, 2, 16);
            v += __shfl_xor(v, 4, 16);
            v += __shfl_xor(v, 8, 16);
            if (l15 == 0) {
                const int p = pairbase + tm * 16 + l4 * 4 + r;
                if (p < NPAIR) {
                    int i, j;
                    ptoij(p, i, j);
                    K[i * NN + j] = v + b3v;
                }
            }
        }
}

// ---------- fallback fp32 MLP kernel (only if ws too small; never expected) ----
#define MC 32
#define JT 128
#define SPAD 132
__global__ __launch_bounds__(256) void mlp_fill(
    const float* __restrict__ x,
    const float* __restrict__ W1, const float* __restrict__ b1,
    const float* __restrict__ W2, const float* __restrict__ b2,
    const float* __restrict__ W3, const float* __restrict__ b3,
    float* __restrict__ K)
{
    const int i  = blockIdx.y;
    const int j0 = blockIdx.x * JT;
    if (j0 + JT - 1 < i) return;
    __shared__ float sA[MD];
    __shared__ float sCw[MD];
    __shared__ float sxj[JT];
    __shared__ float S[MC][SPAD];
    __shared__ float W2t[MC][SPAD];
    const int t = threadIdx.x;
    const float xi = x[i];
    for (int m = t; m < MD; m += 256) {
        const float2 w = reinterpret_cast<const float2*>(W1)[m];
        sA[m]  = fmaf(xi, w.x, b1[m]);
        sCw[m] = w.y;
    }
    if (t < JT) sxj[t] = x[j0 + t];
    const int tk = t & 15;
    const int tj = t >> 4;
    float w3r[8], b2r[8];
#pragma unroll
    for (int kk = 0; kk < 8; kk++) {
        w3r[kk] = W3[tk * 8 + kk];
        b2r[kk] = b2[tk * 8 + kk];
    }
    float acc[8][8];
#pragma unroll
    for (int jj = 0; jj < 8; jj++)
#pragma unroll
        for (int kk = 0; kk < 8; kk++) acc[jj][kk] = 0.f;
    const int jx   = t & 127;
    const int mseg = (t >> 7) * 16;
    __syncthreads();
    const float xjv = sxj[jx];
    for (int m0 = 0; m0 < MD; m0 += MC) {
#pragma unroll
        for (int q = 0; q < 4; q++) {
            const int f   = t + q * 256;
            const int k   = f >> 3;
            const int mm4 = (f & 7) * 4;
            const float4 w = *reinterpret_cast<const float4*>(W2 + k * MD + m0 + mm4);
            W2t[mm4 + 0][k] = w.x;
            W2t[mm4 + 1][k] = w.y;
            W2t[mm4 + 2][k] = w.z;
            W2t[mm4 + 3][k] = w.w;
        }
#pragma unroll
        for (int q = 0; q < 16; q++) {
            const int ml = mseg + q;
            const float z = fmaf(xjv, sCw[m0 + ml], sA[m0 + ml]);
            S[ml][jx] = 1.0f / (1.0f + __expf(-z));
        }
        __syncthreads();
#pragma unroll 4
        for (int mm = 0; mm < MC; mm++) {
            const float4 s0 = *reinterpret_cast<const float4*>(&S[mm][tj * 8]);
            const float4 s1 = *reinterpret_cast<const float4*>(&S[mm][tj * 8 + 4]);
            const float4 w0 = *reinterpret_cast<const float4*>(&W2t[mm][tk * 8]);
            const float4 w1 = *reinterpret_cast<const float4*>(&W2t[mm][tk * 8 + 4]);
            const float sj[8] = {s0.x, s0.y, s0.z, s0.w, s1.x, s1.y, s1.z, s1.w};
            const float wk[8] = {w0.x, w0.y, w0.z, w0.w, w1.x, w1.y, w1.z, w1.w};
#pragma unroll
            for (int jj = 0; jj < 8; jj++)
#pragma unroll
                for (int kk = 0; kk < 8; kk++)
                    acc[jj][kk] = fmaf(sj[jj], wk[kk], acc[jj][kk]);
        }
        __syncthreads();
    }
    const float b3v = b3[0];
#pragma unroll
    for (int jj = 0; jj < 8; jj++) {
        float v = 0.f;
#pragma unroll
        for (int kk = 0; kk < 8; kk++) {
            const float h = acc[jj][kk] + b2r[kk];
            v = fmaf(w3r[kk], fmaxf(h, 0.f), v);
        }
#pragma unroll
        for (int off = 8; off >= 1; off >>= 1)
            v += __shfl_xor(v, off, 16);
        if (tk == 0) {
            const int j = j0 + tj * 8 + jj;
            if (j >= i) K[i * NN + j] = v + b3v;
        }
    }
}

// ---------------- Kernel 2: C = K^T K (768^3 fp32 GEMM) --------------------
__global__ __launch_bounds__(256) void ktk(const float* __restrict__ K,
                                           float* __restrict__ C)
{
    const int b0 = blockIdx.x * 64;
    const int a0 = blockIdx.y * 64;
    __shared__ float Ka[64][68];
    __shared__ float Kb[64][68];
    const int t  = threadIdx.x;
    const int tb = t & 15;
    const int ta = t >> 4;
    float acc[4][4];
#pragma unroll
    for (int u = 0; u < 4; u++)
#pragma unroll
        for (int v = 0; v < 4; v++) acc[u][v] = 0.f;
    const int kmax = (a0 < b0 ? a0 : b0) + 64;
    for (int k0 = 0; k0 < kmax; k0 += 64) {
#pragma unroll
        for (int q = 0; q < 4; q++) {
            const int f  = t + q * 256;
            const int kk = f >> 4;
            const int c4 = (f & 15) * 4;
            *reinterpret_cast<float4*>(&Ka[kk][c4]) =
                *reinterpret_cast<const float4*>(K + (k0 + kk) * NN + a0 + c4);
            *reinterpret_cast<float4*>(&Kb[kk][c4]) =
                *reinterpret_cast<const float4*>(K + (k0 + kk) * NN + b0 + c4);
        }
        __syncthreads();
#pragma unroll 8
        for (int kk = 0; kk < 64; kk++) {
            const float4 av = *reinterpret_cast<const float4*>(&Ka[kk][ta * 4]);
            const float4 bv = *reinterpret_cast<const float4*>(&Kb[kk][tb * 4]);
            const float a4[4] = {av.x, av.y, av.z, av.w};
            const float b4[4] = {bv.x, bv.y, bv.z, bv.w};
#pragma unroll
            for (int u = 0; u < 4; u++)
#pragma unroll
                for (int v = 0; v < 4; v++)
                    acc[u][v] = fmaf(a4[u], b4[v], acc[u][v]);
        }
        __syncthreads();
    }
#pragma unroll
    for (int u = 0; u < 4; u++) {
        float4 o;
        o.x = acc[u][0]; o.y = acc[u][1]; o.z = acc[u][2]; o.w = acc[u][3];
        *reinterpret_cast<float4*>(C + (a0 + ta * 4 + u) * NN + b0 + tb * 4) = o;
    }
}

extern "C" void kernel_launch(void* const* d_in, const int* in_sizes, int n_in,
                              void* d_out, int out_size, void* d_ws, size_t ws_size,
                              hipStream_t stream)
{
    const float* x  = (const float*)d_in[0];
    const float* W1 = (const float*)d_in[1];
    const float* b1 = (const float*)d_in[2];
    const float* W2 = (const float*)d_in[3];
    const float* b2 = (const float*)d_in[4];
    const float* W3 = (const float*)d_in[5];
    const float* b3 = (const float*)d_in[6];
    float* Kmat = (float*)d_ws;                       // 2,359,296 B
    float* C    = (float*)d_out;

    const size_t kBytes = (size_t)NN * NN * sizeof(float);
    const size_t need   = kBytes + 262144;            // + W2 bf16 swizzled

    hipMemsetAsync(Kmat, 0, kBytes, stream);
    if (ws_size >= need) {
        ushort* WhiS = (ushort*)((char*)d_ws + kBytes);
        w2bf16<<<64, 256, 0, stream>>>(W2, WhiS);
        mlp_pairs<<<NPBLK, 256, 0, stream>>>(x, W1, b1, WhiS, b2, W3, b3, Kmat);
    } else {
        mlp_fill<<<dim3(6, NN), 256, 0, stream>>>(x, W1, b1, W2, b2, W3, b3, Kmat);
    }
    ktk<<<dim3(NN / 64, NN / 64), 256, 0, stream>>>(Kmat, C);
}

// Round 5
// 188.741 us; speedup vs baseline: 6.6144x; 1.3566x over previous
//
#include <hip/hip_runtime.h>
#include <hip/hip_bf16.h>

#define NN 768
#define MD 1024
#define NPAIR 295296            // 768*769/2
#define NPBLK 1154              // ceil(NPAIR/256)

typedef __attribute__((ext_vector_type(8))) short s16x8;
typedef __attribute__((ext_vector_type(4))) float f32x4;
typedef __attribute__((ext_vector_type(2))) __bf16 b16x2;

__device__ __forceinline__ ushort bf16_rn(float f) {
    uint u = __builtin_bit_cast(uint, f);
    u += 0x7FFFu + ((u >> 16) & 1u);
    return (ushort)(u >> 16);
}

// inverse triangular index: p -> (i,j), off(i) = i*(1537-i)/2, j = i + p - off(i)
__device__ __forceinline__ void ptoij(int p, int& io, int& jo) {
    const float disc = (float)(1537 * 1537 - 8 * p);
    int i = (int)((1537.0f - sqrtf(disc)) * 0.5f);
    i = i < 0 ? 0 : (i > 767 ? 767 : i);
    while (i > 0 && p < i * (1537 - i) / 2) --i;
    while (i < 767 && p >= (i + 1) * (1536 - i) / 2) ++i;
    io = i;
    jo = i + (p - i * (1537 - i) / 2);
}

#define GLOAD16(gsrc, ldst)                                                        \
    __builtin_amdgcn_global_load_lds(                                              \
        (const __attribute__((address_space(1))) void*)(gsrc),                     \
        (__attribute__((address_space(3))) void*)(ldst), 16, 0, 0)

// ---------- one-time: W2 -> bf16 (RNE), chunk-major + XOR-swizzled -------------
// chunk c (m0=c*64): 128 rows(k) x 128B; byte-in-row = (mloc8*16) ^ ((k&7)<<4)
__global__ __launch_bounds__(256) void w2bf16(const float* __restrict__ W2,
                                              ushort* __restrict__ WhiS)
{
    const int id = blockIdx.x * 256 + threadIdx.x;   // 16384 = 128 k * 128 groups
    const int k = id >> 7;
    const int m = (id & 127) * 8;
    const float4 a = *reinterpret_cast<const float4*>(W2 + k * MD + m);
    const float4 b = *reinterpret_cast<const float4*>(W2 + k * MD + m + 4);
    const float w[8] = {a.x, a.y, a.z, a.w, b.x, b.y, b.z, b.w};
    s16x8 h;
#pragma unroll
    for (int e = 0; e < 8; ++e) h[e] = (short)bf16_rn(w[e]);
    const int c = m >> 6;
    const int mloc8 = (m >> 3) & 7;
    const int byte = (mloc8 * 16) ^ ((k & 7) << 4);
    const int off = c * 8192 + ((k * 128 + byte) >> 1);
    *reinterpret_cast<s16x8*>(&WhiS[off]) = h;
}

// ---- macros for the main loop (use ambient locals) ----------------------------
#define STAGE(cc, buf)                                                       \
    {                                                                        \
        const ushort* sh_ = WhiS + (cc) * 8192;                              \
        _Pragma("unroll")                                                    \
        for (int q_ = 0; q_ < 4; ++q_) {                                     \
            const int off_ = (wv * 4 + q_) * 512;                            \
            GLOAD16(sh_ + off_ + lane * 8, &Wh[buf][off_]);                  \
        }                                                                    \
    }

// weights in sa/sc/sb are pre-scaled by -log2(e):
// u = -z*log2e ; sigma(z) = rcp(1 + 2^u)
#define SIG_CHUNK(cc, dst)                                                   \
    {                                                                        \
        _Pragma("unroll")                                                    \
        for (int ks_ = 0; ks_ < 2; ++ks_) {                                  \
            const int m0_ = (cc) * 64 + ks_ * 32 + l4 * 8;                   \
            const f32x4 a0_ = *reinterpret_cast<const f32x4*>(&sa[m0_]);     \
            const f32x4 a1_ = *reinterpret_cast<const f32x4*>(&sa[m0_ + 4]); \
            const f32x4 c0_ = *reinterpret_cast<const f32x4*>(&sc[m0_]);     \
            const f32x4 c1_ = *reinterpret_cast<const f32x4*>(&sc[m0_ + 4]); \
            const f32x4 b0_ = *reinterpret_cast<const f32x4*>(&sb[m0_]);     \
            const f32x4 b1_ = *reinterpret_cast<const f32x4*>(&sb[m0_ + 4]); \
            _Pragma("unroll")                                                \
            for (int tm_ = 0; tm_ < 4; ++tm_) {                              \
                float s_[8];                                                 \
                _Pragma("unroll")                                            \
                for (int e_ = 0; e_ < 4; ++e_) {                             \
                    const float u0_ = fmaf(xia[tm_], a0_[e_], fmaf(xja[tm_], c0_[e_], b0_[e_])); \
                    const float u1_ = fmaf(xia[tm_], a1_[e_], fmaf(xja[tm_], c1_[e_], b1_[e_])); \
                    s_[e_]     = __builtin_amdgcn_rcpf(1.0f + __builtin_amdgcn_exp2f(u0_)); \
                    s_[e_ + 4] = __builtin_amdgcn_rcpf(1.0f + __builtin_amdgcn_exp2f(u1_)); \
                }                                                            \
                union { s16x8 v; uint u[4]; } fr_;                           \
                _Pragma("unroll")                                            \
                for (int h_ = 0; h_ < 4; ++h_) {                             \
                    b16x2 p_;                                                \
                    p_.x = (__bf16)s_[2 * h_];                               \
                    p_.y = (__bf16)s_[2 * h_ + 1];                           \
                    fr_.u[h_] = __builtin_bit_cast(uint, p_);                \
                }                                                            \
                dst[ks_][tm_] = fr_.v;                                       \
            }                                                                \
        }                                                                    \
    }

#define MFMA_STEP(buf, src)                                                  \
    {                                                                        \
        _Pragma("unroll")                                                    \
        for (int ks_ = 0; ks_ < 2; ++ks_) {                                  \
            _Pragma("unroll")                                                \
            for (int th_ = 0; th_ < 2; ++th_) {                              \
                s16x8 bh_[4];                                                \
                _Pragma("unroll")                                            \
                for (int tn_ = 0; tn_ < 4; ++tn_) {                          \
                    const int k_ = th_ * 64 + tn_ * 16 + l15;                \
                    const int byte_ = (ks_ * 64 + l4 * 16) ^ ((k_ & 7) << 4);\
                    const int idx_ = (k_ * 128 + byte_) >> 1;                \
                    bh_[tn_] = *reinterpret_cast<const s16x8*>(&Wh[buf][idx_]); \
                }                                                            \
                __builtin_amdgcn_s_setprio(1);                               \
                _Pragma("unroll")                                            \
                for (int tm_ = 0; tm_ < 4; ++tm_)                            \
                    _Pragma("unroll")                                        \
                    for (int tn_ = 0; tn_ < 4; ++tn_)                        \
                        acc[tm_][th_][tn_] = __builtin_amdgcn_mfma_f32_16x16x32_bf16( \
                            src[ks_][tm_], bh_[tn_], acc[tm_][th_][tn_], 0, 0, 0);    \
                __builtin_amdgcn_s_setprio(0);                               \
            }                                                                \
        }                                                                    \
    }

// ---------- main: pair-flattened MLP, 1-term bf16, single A-frag set ----------
__global__ __launch_bounds__(256, 2) void mlp_pairs(
    const float* __restrict__ x,
    const float* __restrict__ W1, const float* __restrict__ b1,
    const ushort* __restrict__ WhiS,
    const float* __restrict__ b2, const float* __restrict__ W3,
    const float* __restrict__ b3, float* __restrict__ K)
{
    __shared__ __align__(16) float sa[MD], sc[MD], sb[MD];
    __shared__ __align__(16) ushort Wh[2][8192];

    const int t = threadIdx.x;
    const int lane = t & 63, wv = t >> 6;
    const int l15 = lane & 15, l4 = lane >> 4;

    const float NL2E = -1.4426950408889634f;   // -log2(e), folded into layer-1
    for (int m = t; m < MD; m += 256) {
        const float2 w = reinterpret_cast<const float2*>(W1)[m];
        sa[m] = w.x * NL2E;
        sc[m] = w.y * NL2E;
        sb[m] = b1[m] * NL2E;
    }

    const int pairbase = blockIdx.x * 256 + wv * 64;

    float xia[4], xja[4];
#pragma unroll
    for (int tm = 0; tm < 4; ++tm) {
        const int p = pairbase + tm * 16 + l15;
        if (p < NPAIR) {
            int i, j;
            ptoij(p, i, j);
            xia[tm] = x[i];
            xja[tm] = x[j];
        } else {
            xia[tm] = 0.f;
            xja[tm] = 0.f;
        }
    }

    f32x4 acc[4][2][4];
#pragma unroll
    for (int a = 0; a < 4; ++a)
#pragma unroll
        for (int th = 0; th < 2; ++th)
#pragma unroll
            for (int b = 0; b < 4; ++b) acc[a][th][b] = (f32x4){0.f, 0.f, 0.f, 0.f};

    STAGE(0, 0);
    __syncthreads();                 // sa/sc/sb written AND Wh[0] staged

    s16x8 ah[2][4];
    for (int c = 0; c < 16; ++c) {
        if (c < 15) STAGE(c + 1, (c + 1) & 1);   // async into other buffer, 0 regs
        SIG_CHUNK(c, ah);                        // VALU while loads fly
        MFMA_STEP(c & 1, ah);
        __syncthreads();             // drains vmcnt (next buf ready) + lgkm reads
    }

    // epilogue: v = sum_k W3[k]*relu(h2 + b2[k]) + b3; reduce over 16 lanes (k)
    float w3v[2][4], b2v[2][4];
#pragma unroll
    for (int th = 0; th < 2; ++th)
#pragma unroll
        for (int tn = 0; tn < 4; ++tn) {
            const int k = th * 64 + tn * 16 + l15;
            w3v[th][tn] = W3[k];
            b2v[th][tn] = b2[k];
        }
    const float b3v = b3[0];
#pragma unroll
    for (int tm = 0; tm < 4; ++tm)
#pragma unroll
        for (int r = 0; r < 4; ++r) {
            float v = 0.f;
#pragma unroll
            for (int th = 0; th < 2; ++th)
#pragma unroll
                for (int tn = 0; tn < 4; ++tn)
                    v = fmaf(w3v[th][tn], fmaxf(acc[tm][th][tn][r] + b2v[th][tn], 0.f), v);
            v += __shfl_xor(v, 1, 16);
            v += __shfl_xor(v, 2, 16);
            v += __shfl_xor(v, 4, 16);
            v += __shfl_xor(v, 8, 16);
            if (l15 == 0) {
                const int p = pairbase + tm * 16 + l4 * 4 + r;
                if (p < NPAIR) {
                    int i, j;
                    ptoij(p, i, j);
                    K[i * NN + j] = v + b3v;
                }
            }
        }
}

// ---------- fallback fp32 MLP kernel (only if ws too small; never expected) ----
#define MC 32
#define JT 128
#define SPAD 132
__global__ __launch_bounds__(256) void mlp_fill(
    const float* __restrict__ x,
    const float* __restrict__ W1, const float* __restrict__ b1,
    const float* __restrict__ W2, const float* __restrict__ b2,
    const float* __restrict__ W3, const float* __restrict__ b3,
    float* __restrict__ K)
{
    const int i  = blockIdx.y;
    const int j0 = blockIdx.x * JT;
    if (j0 + JT - 1 < i) return;
    __shared__ float sA[MD];
    __shared__ float sCw[MD];
    __shared__ float sxj[JT];
    __shared__ float S[MC][SPAD];
    __shared__ float W2t[MC][SPAD];
    const int t = threadIdx.x;
    const float xi = x[i];
    for (int m = t; m < MD; m += 256) {
        const float2 w = reinterpret_cast<const float2*>(W1)[m];
        sA[m]  = fmaf(xi, w.x, b1[m]);
        sCw[m] = w.y;
    }
    if (t < JT) sxj[t] = x[j0 + t];
    const int tk = t & 15;
    const int tj = t >> 4;
    float w3r[8], b2r[8];
#pragma unroll
    for (int kk = 0; kk < 8; kk++) {
        w3r[kk] = W3[tk * 8 + kk];
        b2r[kk] = b2[tk * 8 + kk];
    }
    float acc[8][8];
#pragma unroll
    for (int jj = 0; jj < 8; jj++)
#pragma unroll
        for (int kk = 0; kk < 8; kk++) acc[jj][kk] = 0.f;
    const int jx   = t & 127;
    const int mseg = (t >> 7) * 16;
    __syncthreads();
    const float xjv = sxj[jx];
    for (int m0 = 0; m0 < MD; m0 += MC) {
#pragma unroll
        for (int q = 0; q < 4; q++) {
            const int f   = t + q * 256;
            const int k   = f >> 3;
            const int mm4 = (f & 7) * 4;
            const float4 w = *reinterpret_cast<const float4*>(W2 + k * MD + m0 + mm4);
            W2t[mm4 + 0][k] = w.x;
            W2t[mm4 + 1][k] = w.y;
            W2t[mm4 + 2][k] = w.z;
            W2t[mm4 + 3][k] = w.w;
        }
#pragma unroll
        for (int q = 0; q < 16; q++) {
            const int ml = mseg + q;
            const float z = fmaf(xjv, sCw[m0 + ml], sA[m0 + ml]);
            S[ml][jx] = 1.0f / (1.0f + __expf(-z));
        }
        __syncthreads();
#pragma unroll 4
        for (int mm = 0; mm < MC; mm++) {
            const float4 s0 = *reinterpret_cast<const float4*>(&S[mm][tj * 8]);
            const float4 s1 = *reinterpret_cast<const float4*>(&S[mm][tj * 8 + 4]);
            const float4 w0 = *reinterpret_cast<const float4*>(&W2t[mm][tk * 8]);
            const float4 w1 = *reinterpret_cast<const float4*>(&W2t[mm][tk * 8 + 4]);
            const float sj[8] = {s0.x, s0.y, s0.z, s0.w, s1.x, s1.y, s1.z, s1.w};
            const float wk[8] = {w0.x, w0.y, w0.z, w0.w, w1.x, w1.y, w1.z, w1.w};
#pragma unroll
            for (int jj = 0; jj < 8; jj++)
#pragma unroll
                for (int kk = 0; kk < 8; kk++)
                    acc[jj][kk] = fmaf(sj[jj], wk[kk], acc[jj][kk]);
        }
        __syncthreads();
    }
    const float b3v = b3[0];
#pragma unroll
    for (int jj = 0; jj < 8; jj++) {
        float v = 0.f;
#pragma unroll
        for (int kk = 0; kk < 8; kk++) {
            const float h = acc[jj][kk] + b2r[kk];
            v = fmaf(w3r[kk], fmaxf(h, 0.f), v);
        }
#pragma unroll
        for (int off = 8; off >= 1; off >>= 1)
            v += __shfl_xor(v, off, 16);
        if (tk == 0) {
            const int j = j0 + tj * 8 + jj;
            if (j >= i) K[i * NN + j] = v + b3v;
        }
    }
}

// ---------------- Kernel 2: C = K^T K (768^3 fp32 GEMM) --------------------
__global__ __launch_bounds__(256) void ktk(const float* __restrict__ K,
                                           float* __restrict__ C)
{
    const int b0 = blockIdx.x * 64;
    const int a0 = blockIdx.y * 64;
    __shared__ float Ka[64][68];
    __shared__ float Kb[64][68];
    const int t  = threadIdx.x;
    const int tb = t & 15;
    const int ta = t >> 4;
    float acc[4][4];
#pragma unroll
    for (int u = 0; u < 4; u++)
#pragma unroll
        for (int v = 0; v < 4; v++) acc[u][v] = 0.f;
    const int kmax = (a0 < b0 ? a0 : b0) + 64;
    for (int k0 = 0; k0 < kmax; k0 += 64) {
#pragma unroll
        for (int q = 0; q < 4; q++) {
            const int f  = t + q * 256;
            const int kk = f >> 4;
            const int c4 = (f & 15) * 4;
            *reinterpret_cast<float4*>(&Ka[kk][c4]) =
                *reinterpret_cast<const float4*>(K + (k0 + kk) * NN + a0 + c4);
            *reinterpret_cast<float4*>(&Kb[kk][c4]) =
                *reinterpret_cast<const float4*>(K + (k0 + kk) * NN + b0 + c4);
        }
        __syncthreads();
#pragma unroll 8
        for (int kk = 0; kk < 64; kk++) {
            const float4 av = *reinterpret_cast<const float4*>(&Ka[kk][ta * 4]);
            const float4 bv = *reinterpret_cast<const float4*>(&Kb[kk][tb * 4]);
            const float a4[4] = {av.x, av.y, av.z, av.w};
            const float b4[4] = {bv.x, bv.y, bv.z, bv.w};
#pragma unroll
            for (int u = 0; u < 4; u++)
#pragma unroll
                for (int v = 0; v < 4; v++)
                    acc[u][v] = fmaf(a4[u], b4[v], acc[u][v]);
        }
        __syncthreads();
    }
#pragma unroll
    for (int u = 0; u < 4; u++) {
        float4 o;
        o.x = acc[u][0]; o.y = acc[u][1]; o.z = acc[u][2]; o.w = acc[u][3];
        *reinterpret_cast<float4*>(C + (a0 + ta * 4 + u) * NN + b0 + tb * 4) = o;
    }
}

extern "C" void kernel_launch(void* const* d_in, const int* in_sizes, int n_in,
                              void* d_out, int out_size, void* d_ws, size_t ws_size,
                              hipStream_t stream)
{
    const float* x  = (const float*)d_in[0];
    const float* W1 = (const float*)d_in[1];
    const float* b1 = (const float*)d_in[2];
    const float* W2 = (const float*)d_in[3];
    const float* b2 = (const float*)d_in[4];
    const float* W3 = (const float*)d_in[5];
    const float* b3 = (const float*)d_in[6];
    float* Kmat = (float*)d_ws;                       // 2,359,296 B
    float* C    = (float*)d_out;

    const size_t kBytes = (size_t)NN * NN * sizeof(float);
    const size_t need   = kBytes + 262144;            // + W2 bf16 swizzled

    hipMemsetAsync(Kmat, 0, kBytes, stream);
    if (ws_size >= need) {
        ushort* WhiS = (ushort*)((char*)d_ws + kBytes);
        w2bf16<<<64, 256, 0, stream>>>(W2, WhiS);
        mlp_pairs<<<NPBLK, 256, 0, stream>>>(x, W1, b1, WhiS, b2, W3, b3, Kmat);
    } else {
        mlp_fill<<<dim3(6, NN), 256, 0, stream>>>(x, W1, b1, W2, b2, W3, b3, Kmat);
    }
    ktk<<<dim3(NN / 64, NN / 64), 256, 0, stream>>>(Kmat, C);
}